// Round 8
// baseline (211.846 us; speedup 1.0000x reference)
//
#include <hip/hip_runtime.h>
#include <math.h>

typedef unsigned long long u64;
typedef unsigned int u32;

#define B_ 2
#define F_ 8
#define P_ 2048
#define T_ 7                   // F-1
#define ROWS (B_*T_*P_)        // 28672
#define SENT_OU 0xFFFFFFFFu

// ---- keys: u64 = (ordered_f32_dist << 16) | idx ; integer order == exact
// (dist, idx) lexicographic order, matching JAX top_k lower-index tie-break.
#define CEU(arr,a,b) do { u64 _x=arr[a], _y=arr[b]; bool _s=(_y<_x); arr[a]=_s?_y:_x; arr[b]=_s?_x:_y; } while(0)

// Batcher odd-even mergesort, 8 elements, 19 comparators
__device__ __forceinline__ void sort8u(u64* k) {
  CEU(k,0,1); CEU(k,2,3); CEU(k,4,5); CEU(k,6,7);
  CEU(k,0,2); CEU(k,1,3); CEU(k,4,6); CEU(k,5,7);
  CEU(k,1,2); CEU(k,5,6);
  CEU(k,0,4); CEU(k,1,5); CEU(k,2,6); CEU(k,3,7);
  CEU(k,2,4); CEU(k,3,5);
  CEU(k,1,2); CEU(k,3,4); CEU(k,5,6);
}

// A,B sorted ascending -> A = lowest 8 of the 16, sorted
__device__ __forceinline__ void low8u(u64* A, const u64* Bv) {
#pragma unroll
  for (int i = 0; i < 8; ++i) { u64 b = Bv[7-i]; A[i] = (b < A[i]) ? b : A[i]; }
#pragma unroll
  for (int st = 4; st >= 1; st >>= 1) {
#pragma unroll
    for (int i = 0; i < 8; ++i) {
      if ((i & st) == 0) { CEU(A, i, i + st); }
    }
  }
}

// ---- quarter(16-lane)-local butterfly reductions via DPP: result in ALL lanes ----
__device__ __forceinline__ u32 bfly16_min_u32(u32 x) {
  u32 t;
  t = (u32)__builtin_amdgcn_update_dpp((int)x,(int)x,0x0B1,0xF,0xF,false); x = t<x?t:x;
  t = (u32)__builtin_amdgcn_update_dpp((int)x,(int)x,0x04E,0xF,0xF,false); x = t<x?t:x;
  t = (u32)__builtin_amdgcn_update_dpp((int)x,(int)x,0x141,0xF,0xF,false); x = t<x?t:x;
  t = (u32)__builtin_amdgcn_update_dpp((int)x,(int)x,0x140,0xF,0xF,false); x = t<x?t:x;
  return x;
}
__device__ __forceinline__ float bfly16_sum_f32(float x) {
  float t;
  t = __uint_as_float((u32)__builtin_amdgcn_update_dpp((int)__float_as_uint(x),(int)__float_as_uint(x),0x0B1,0xF,0xF,false)); x += t;
  t = __uint_as_float((u32)__builtin_amdgcn_update_dpp((int)__float_as_uint(x),(int)__float_as_uint(x),0x04E,0xF,0xF,false)); x += t;
  t = __uint_as_float((u32)__builtin_amdgcn_update_dpp((int)__float_as_uint(x),(int)__float_as_uint(x),0x141,0xF,0xF,false)); x += t;
  t = __uint_as_float((u32)__builtin_amdgcn_update_dpp((int)__float_as_uint(x),(int)__float_as_uint(x),0x140,0xF,0xF,false)); x += t;
  return x;
}

// ---------------- Kernel A: bearing quaternions + |q|^2 prepack ----------------
__global__ __launch_bounds__(256) void kA_bearing(const float4* __restrict__ pts,
                                                  float4* __restrict__ bq,
                                                  float4* __restrict__ pts2) {
  int bf = blockIdx.x;                // b*F + f
  const float4* base = pts + (size_t)bf * P_;
  int tid = threadIdx.x;
  float x[8], y[8], z[8];
  float mnx =  INFINITY, mny =  INFINITY, mnz =  INFINITY;
  float mxx = -INFINITY, mxy = -INFINITY, mxz = -INFINITY;
#pragma unroll
  for (int i = 0; i < 8; ++i) {
    float4 v = base[tid + i*256];
    x[i]=v.x; y[i]=v.y; z[i]=v.z;
    mnx=fminf(mnx,v.x); mny=fminf(mny,v.y); mnz=fminf(mnz,v.z);
    mxx=fmaxf(mxx,v.x); mxy=fmaxf(mxy,v.y); mxz=fmaxf(mxz,v.z);
  }
#pragma unroll
  for (int off = 32; off >= 1; off >>= 1) {
    mnx=fminf(mnx,__shfl_xor(mnx,off)); mny=fminf(mny,__shfl_xor(mny,off)); mnz=fminf(mnz,__shfl_xor(mnz,off));
    mxx=fmaxf(mxx,__shfl_xor(mxx,off)); mxy=fmaxf(mxy,__shfl_xor(mxy,off)); mxz=fmaxf(mxz,__shfl_xor(mxz,off));
  }
  __shared__ float red[4][6];
  int wid = tid >> 6, lane = tid & 63;
  if (lane == 0) { red[wid][0]=mnx; red[wid][1]=mny; red[wid][2]=mnz;
                   red[wid][3]=mxx; red[wid][4]=mxy; red[wid][5]=mxz; }
  __syncthreads();
  mnx=fminf(fminf(red[0][0],red[1][0]),fminf(red[2][0],red[3][0]));
  mny=fminf(fminf(red[0][1],red[1][1]),fminf(red[2][1],red[3][1]));
  mnz=fminf(fminf(red[0][2],red[1][2]),fminf(red[2][2],red[3][2]));
  mxx=fmaxf(fmaxf(red[0][3],red[1][3]),fmaxf(red[2][3],red[3][3]));
  mxy=fmaxf(fmaxf(red[0][4],red[1][4]),fmaxf(red[2][4],red[3][4]));
  mxz=fmaxf(fmaxf(red[0][5],red[1][5]),fmaxf(red[2][5],red[3][5]));
  float cx=(mnx+mxx)*0.5f, cy=(mny+mxy)*0.5f, cz=(mnz+mxz)*0.5f;
#pragma unroll
  for (int i = 0; i < 8; ++i) {
    float dx=x[i]-cx, dy=y[i]-cy, dz=z[i]-cz;
    float n = sqrtf(((dx*dx) + dy*dy) + dz*dz);
    n = fmaxf(n, 1e-12f);
    float dxn = dx/n, dyn = dy/n, dzn = dz/n;
    float dotc = fminf(fmaxf(dyn, -0.99999990f), 0.99999990f);
    float half = acosf(dotc) * 0.5f;
    float an = sqrtf(dzn*dzn + dxn*dxn);
    an = fmaxf(an, 1e-12f);
    float axx = dzn/an, axz = (-dxn)/an;
    float s = sinf(half), w = cosf(half);
    bq[(size_t)bf*P_ + tid + i*256] = make_float4(w, axx*s, 0.f, axz*s);
    float qs = fmaf(x[i],x[i], fmaf(y[i],y[i], z[i]*z[i]));
    pts2[(size_t)bf*P_ + tid + i*256] = make_float4(x[i], y[i], z[i], qs);
  }
}

// ---------------- Kernel B: forward quaternions ----------------
__global__ __launch_bounds__(256) void kB_qfwd(const float4* __restrict__ bq,
                                               float4* __restrict__ qf) {
  int i = blockIdx.x*256 + threadIdx.x;   // over B*T*P
  int p = i & (P_-1);
  int t = (i >> 11) % T_;
  int b = i / (T_*P_);
  float4 s = bq[((size_t)(b*F_ + t))*P_ + p];       // frame t (src)
  float4 a = bq[((size_t)(b*F_ + t + 1))*P_ + p];   // frame t+1 (tgt)
  float aw=a.x, ax=a.y, ay=a.z, az=a.w;
  float bw=s.x, bx=-s.y, by=-s.z, bz=-s.w;          // conj
  float w  = ((aw*bw - ax*bx) - ay*by) - az*bz;
  float xo = ((aw*bx + ax*bw) + ay*bz) - az*by;
  float yo = ((aw*by - ax*bz) + ay*bw) + az*bx;
  float zo = ((aw*bz + ax*by) - ay*bx) + az*bw;
  float n = sqrtf(((w*w + xo*xo) + yo*yo) + zo*zo);
  n = fmaxf(n, 1e-12f);
  qf[i] = make_float4(w/n, xo/n, yo/n, zo/n);
}

// ---------------- Kernel C: top-40, quarter-wave rows, 4 waves/block ----------------
__device__ __forceinline__ u64 mkkey(float4 c, u32 q,
                                     float px, float py, float pz, float ps) {
  float dot = fmaf(px, c.x, fmaf(py, c.y, pz*c.z));
  float v = (2.f*dot - ps) - c.w;      // = reference neg_dist
  float nd = -v;                       // ascending distance
  u32 u = __float_as_uint(nd);
  u32 ou = (u & 0x80000000u) ? ~u : (u | 0x80000000u);
  return ((u64)ou << 16) | q;
}

// exact popstep with in-loop refill (fallback path only; ~never hot)
__device__ __forceinline__ void popstep_exact(u32 (&OU)[8], u32 (&IX)[8],
                                              u32& LOU, u32& LIX, u32& CAP, int imod,
                                              int slot, const float4* __restrict__ pbase,
                                              float px, float py, float pz, float ps) {
  if (__any(OU[0] == SENT_OU)) {
    bool need = (OU[0] == SENT_OU);
    u64 lastK = ((u64)LOU << 16) | LIX;
    u64 best = ~0ull;
    for (int j = 0; j < 128; ++j) {
      u32 q = (u32)(j*16 + slot);
      float4 c = pbase[q];
      u64 kk = mkkey(c, q, px,py,pz,ps);
      if (kk > lastK && kk < best) best = kk;
    }
    if (need && best != ~0ull) { OU[0] = (u32)(best >> 16); IX[0] = (u32)(best & 0xffffu); }
  }
  u32 qmin = bfly16_min_u32(OU[0]);
  bool meq = (OU[0] == qmin);
  u32 tt   = meq ? IX[0] : 0xFFFFFFFFu;
  u32 widx = bfly16_min_u32(tt);
  bool iam = meq && (IX[0] == widx);
  CAP = (slot == imod) ? widx : CAP;
  LOU = iam ? qmin : LOU;
  LIX = iam ? widx : LIX;
#pragma unroll
  for (int jj = 0; jj < 7; ++jj) {
    OU[jj] = iam ? OU[jj+1] : OU[jj];
    IX[jj] = iam ? IX[jj+1] : IX[jj];
  }
  OU[7] = iam ? SENT_OU : OU[7];
}

// tight popstep: no refill, no last-key tracking; counts pops per lane
__device__ __forceinline__ void popstep_fast(u32 (&OU)[8], u32 (&IX)[8],
                                             u32& CAP, u32& popped, int imod, int slot) {
  u32 qmin = bfly16_min_u32(OU[0]);
  bool meq = (OU[0] == qmin);
  u32 tt   = meq ? IX[0] : 0xFFFFFFFFu;
  u32 widx = bfly16_min_u32(tt);
  bool iam = meq && (IX[0] == widx);
  CAP = (slot == imod) ? widx : CAP;
  popped += iam ? 1u : 0u;
#pragma unroll
  for (int jj = 0; jj < 7; ++jj) {
    OU[jj] = iam ? OU[jj+1] : OU[jj];
    IX[jj] = iam ? IX[jj+1] : IX[jj];
  }
  OU[7] = iam ? SENT_OU : OU[7];
}

__global__ __launch_bounds__(256) void kC_select(const float4* __restrict__ pts2,
                                                 const float4* __restrict__ qf,
                                                 float* __restrict__ S) {
  int lane = threadIdx.x & 63;
  int wid  = threadIdx.x >> 6;         // wave within block (0..3)
  int slot = lane & 15;                // position within 16-lane quarter
  int quarter = lane >> 4;             // 0..3
  int gid = blockIdx.x * 16 + wid * 4; // first row of this wave
  int p0 = gid & (P_-1);               // 16 divides 2048 -> same tile across waves
  int bt = gid >> 11;                  // b*7 + t
  int t  = bt % T_;
  int b  = bt / T_;
  const float4* pbase = pts2 + (size_t)(b*F_ + t) * P_;

  int prow = p0 + quarter;             // this quarter's row
  float4 pw = pbase[prow];
  float px=pw.x, py=pw.y, pz=pw.z, ps=pw.w;

  // ---- sort phase: per lane 128 candidates (j*16+slot), keep sorted top-8 ----
  u64 acc[8];
  {
    u64 k0[8];
#pragma unroll
    for (int u = 0; u < 8; ++u) { float4 c = pbase[u*16 + slot];
      k0[u] = mkkey(c, (u32)(u*16 + slot), px,py,pz,ps); }
    sort8u(k0);
#pragma unroll
    for (int j = 0; j < 8; ++j) acc[j] = k0[j];
  }
#pragma unroll 2
  for (int batch = 1; batch < 16; ++batch) {
    int qb = batch*128 + slot;
    float4 c[8];
#pragma unroll
    for (int u = 0; u < 8; ++u) c[u] = pbase[qb + u*16];
    u64 k[8];
#pragma unroll
    for (int u = 0; u < 8; ++u) k[u] = mkkey(c[u], (u32)(qb + u*16), px,py,pz,ps);
    sort8u(k);
    low8u(acc, k);
  }

  // unpack into register queue + backup for the (rare) exact fallback
  u32 OU[8], IX[8], BOU[8], BIX[8];
#pragma unroll
  for (int j = 0; j < 8; ++j) {
    OU[j] = (u32)(acc[j] >> 16); IX[j] = (u32)(acc[j] & 0xffffu);
    BOU[j] = OU[j]; BIX[j] = IX[j];
  }

  u32 cap1=0, cap2=0, cap3=0, popped=0;

#pragma unroll 1
  for (int i = 0; i < 16; ++i)         // winners 0..15 -> cap1[slot==i]
    popstep_fast(OU, IX, cap1, popped, i, slot);
#pragma unroll 1
  for (int i = 0; i < 16; ++i)         // winners 16..31 -> cap2
    popstep_fast(OU, IX, cap2, popped, i, slot);
#pragma unroll 1
  for (int i = 0; i < 8; ++i)          // winners 32..39 -> cap3 (slots 0..7)
    popstep_fast(OU, IX, cap3, popped, i, slot);

  // conservative exactness check: a lane that emptied its 8-deep queue might
  // have owned a 9th element of the true top-40. Redo exactly (cold, ~24%).
  if (__any(popped >= 8u)) {
#pragma unroll
    for (int j = 0; j < 8; ++j) { OU[j] = BOU[j]; IX[j] = BIX[j]; }
    u32 lou = 0, lix = 0;
    cap1 = cap2 = cap3 = 0;
#pragma unroll 1
    for (int i = 0; i < 16; ++i)
      popstep_exact(OU, IX, lou, lix, cap1, i, slot, pbase, px,py,pz,ps);
#pragma unroll 1
    for (int i = 0; i < 16; ++i)
      popstep_exact(OU, IX, lou, lix, cap2, i, slot, pbase, px,py,pz,ps);
#pragma unroll 1
    for (int i = 0; i < 8; ++i)
      popstep_exact(OU, IX, lou, lix, cap3, i, slot, pbase, px,py,pz,ps);
  }

  // ---- epilogue: geodesic sums ----
  int row = bt*P_ + prow;
  const float4* qbt = qf + (size_t)bt * P_;
  float4 qp = qf[row];

  float4 n; float d;
  n = qbt[cap1]; d = ((qp.x*n.x + qp.y*n.y) + qp.z*n.z) + qp.w*n.w;
  float g1 = 2.f * acosf(fminf(fabsf(d), 0.99999990f));
  n = qbt[cap2]; d = ((qp.x*n.x + qp.y*n.y) + qp.z*n.z) + qp.w*n.w;
  float g2 = 2.f * acosf(fminf(fabsf(d), 0.99999990f));
  n = qbt[cap3]; d = ((qp.x*n.x + qp.y*n.y) + qp.z*n.z) + qp.w*n.w;
  float g3 = (slot < 8) ? 2.f * acosf(fminf(fabsf(d), 0.99999990f)) : 0.f;

  float s40 = bfly16_sum_f32(g1 + g2 + g3);
  float s15 = bfly16_sum_f32((slot < 15) ? g1 : 0.f);
  float s5  = bfly16_sum_f32((slot < 5)  ? g1 : 0.f);

  if (slot == 0) {
    S[0*ROWS + row] = s5  / 5.f;
    S[1*ROWS + row] = s15 / 15.f;
    S[2*ROWS + row] = s40 / 40.f;
  }
}

// ---------------- Kernel E: mean over t, median, output (all 3 scales, 1 block) ----
__global__ __launch_bounds__(1024) void kE_final(const float* __restrict__ S,
                                                 float* __restrict__ out) {
  int tid = threadIdx.x;
  __shared__ float srt[3][4096];
  float m[3][4];
#pragma unroll
  for (int k = 0; k < 3; ++k) {
    const float* Sk = S + (size_t)k * ROWS;
#pragma unroll
    for (int u = 0; u < 4; ++u) {
      int j = tid + u*1024;            // j = b*2048 + p
      int b = j >> 11, p = j & 2047;
      float acc = 0.f;
#pragma unroll
      for (int t = 0; t < 7; ++t) acc += Sk[(b*7 + t)*2048 + p];
      m[k][u] = acc / 7.f;
      srt[k][j] = m[k][u];
    }
  }
  __syncthreads();
  for (int size = 2; size <= 4096; size <<= 1) {
    for (int stride = size >> 1; stride > 0; stride >>= 1) {
      for (int c = tid; c < 2048; c += 1024) {
        int i = 2*c - (c & (stride - 1));
        int j = i + stride;
        bool up = ((i & size) == 0);
#pragma unroll
        for (int k = 0; k < 3; ++k) {
          float a = srt[k][i], bb = srt[k][j];
          if ((a > bb) == up) { srt[k][i] = bb; srt[k][j] = a; }
        }
      }
      __syncthreads();
    }
  }
#pragma unroll
  for (int k = 0; k < 3; ++k) {
    float scale = fmaxf(srt[k][2047], 1e-6f);  // lower median of 4096
    bool pos = srt[k][4095] > 0.f;
#pragma unroll
    for (int u = 0; u < 4; ++u) {
      int j = tid + u*1024;
      int b = j >> 11, p = j & 2047;
      float r = pos ? expf(-m[k][u]/scale) : 1.f;
      float* ob = out + ((size_t)(b*3 + k)*8)*2048 + p;
#pragma unroll
      for (int f = 0; f < 8; ++f) ob[f*2048] = r;
    }
  }
}

extern "C" void kernel_launch(void* const* d_in, const int* in_sizes, int n_in,
                              void* d_out, int out_size, void* d_ws, size_t ws_size,
                              hipStream_t stream) {
  (void)in_sizes; (void)n_in; (void)out_size; (void)ws_size;
  const float4* pts = (const float4*)d_in[0];
  float* ws = (float*)d_ws;
  float4* bq   = (float4*)ws;                     // B*F*P*4   = 131072 floats
  float4* qfw  = (float4*)(ws + 131072);          // B*T*P*4   = 114688 floats
  float*  S    = ws + 131072 + 114688;            // 3*ROWS    =  86016 floats
  float4* pts2 = (float4*)(ws + 131072 + 114688 + 86016);  // B*F*P*4 = 131072 floats
  float*  out = (float*)d_out;

  hipLaunchKernelGGL(kA_bearing, dim3(B_*F_), dim3(256), 0, stream, pts, bq, pts2);
  hipLaunchKernelGGL(kB_qfwd,    dim3(ROWS/256), dim3(256), 0, stream, bq, qfw);
  hipLaunchKernelGGL(kC_select,  dim3(ROWS/16), dim3(256), 0, stream, pts2, qfw, S);
  hipLaunchKernelGGL(kE_final,   dim3(1), dim3(1024), 0, stream, S, out);
}

// Round 9
// 169.501 us; speedup vs baseline: 1.2498x; 1.2498x over previous
//
#include <hip/hip_runtime.h>
#include <math.h>

typedef unsigned long long u64;
typedef unsigned int u32;

#define B_ 2
#define F_ 8
#define P_ 2048
#define T_ 7                   // F-1
#define ROWS (B_*T_*P_)        // 28672
#define SENT_OU 0xFFFFFFFFu

// ---- keys as positive-normal doubles: bit pattern 0x4000.. | ou<<16 | idx ----
// positive doubles: IEEE ordering == integer ordering -> CE = v_min_f64+v_max_f64
// (r8 measured: u64 integer CE is 1.4x MORE VALU cycles; f64 CE is the winner)
#define CED(arr,a,b) do { double _x=arr[a], _y=arr[b]; arr[a]=fmin(_x,_y); arr[b]=fmax(_x,_y); } while(0)

// Batcher odd-even mergesort, 8 elements, 19 comparators
__device__ __forceinline__ void sort8d(double* k) {
  CED(k,0,1); CED(k,2,3); CED(k,4,5); CED(k,6,7);
  CED(k,0,2); CED(k,1,3); CED(k,4,6); CED(k,5,7);
  CED(k,1,2); CED(k,5,6);
  CED(k,0,4); CED(k,1,5); CED(k,2,6); CED(k,3,7);
  CED(k,2,4); CED(k,3,5);
  CED(k,1,2); CED(k,3,4); CED(k,5,6);
}

// A,B sorted ascending -> A = lowest 8 of the 16, sorted
__device__ __forceinline__ void low8(double* A, const double* Bv) {
#pragma unroll
  for (int i = 0; i < 8; ++i) A[i] = fmin(A[i], Bv[7-i]);   // bitonic
#pragma unroll
  for (int st = 4; st >= 1; st >>= 1) {
#pragma unroll
    for (int i = 0; i < 8; ++i) {
      if ((i & st) == 0) { CED(A, i, i + st); }
    }
  }
}

// ---- quarter(16-lane)-local butterfly reductions via DPP: result in ALL lanes ----
__device__ __forceinline__ u32 bfly16_min_u32(u32 x) {
  u32 t;
  t = (u32)__builtin_amdgcn_update_dpp((int)x,(int)x,0x0B1,0xF,0xF,false); x = t<x?t:x;
  t = (u32)__builtin_amdgcn_update_dpp((int)x,(int)x,0x04E,0xF,0xF,false); x = t<x?t:x;
  t = (u32)__builtin_amdgcn_update_dpp((int)x,(int)x,0x141,0xF,0xF,false); x = t<x?t:x;
  t = (u32)__builtin_amdgcn_update_dpp((int)x,(int)x,0x140,0xF,0xF,false); x = t<x?t:x;
  return x;
}
__device__ __forceinline__ float bfly16_sum_f32(float x) {
  float t;
  t = __uint_as_float((u32)__builtin_amdgcn_update_dpp((int)__float_as_uint(x),(int)__float_as_uint(x),0x0B1,0xF,0xF,false)); x += t;
  t = __uint_as_float((u32)__builtin_amdgcn_update_dpp((int)__float_as_uint(x),(int)__float_as_uint(x),0x04E,0xF,0xF,false)); x += t;
  t = __uint_as_float((u32)__builtin_amdgcn_update_dpp((int)__float_as_uint(x),(int)__float_as_uint(x),0x141,0xF,0xF,false)); x += t;
  t = __uint_as_float((u32)__builtin_amdgcn_update_dpp((int)__float_as_uint(x),(int)__float_as_uint(x),0x140,0xF,0xF,false)); x += t;
  return x;
}

// ---------------- Kernel A: bearing quaternions + |q|^2 prepack ----------------
__global__ __launch_bounds__(256) void kA_bearing(const float4* __restrict__ pts,
                                                  float4* __restrict__ bq,
                                                  float4* __restrict__ pts2) {
  int bf = blockIdx.x;                // b*F + f
  const float4* base = pts + (size_t)bf * P_;
  int tid = threadIdx.x;
  float x[8], y[8], z[8];
  float mnx =  INFINITY, mny =  INFINITY, mnz =  INFINITY;
  float mxx = -INFINITY, mxy = -INFINITY, mxz = -INFINITY;
#pragma unroll
  for (int i = 0; i < 8; ++i) {
    float4 v = base[tid + i*256];
    x[i]=v.x; y[i]=v.y; z[i]=v.z;
    mnx=fminf(mnx,v.x); mny=fminf(mny,v.y); mnz=fminf(mnz,v.z);
    mxx=fmaxf(mxx,v.x); mxy=fmaxf(mxy,v.y); mxz=fmaxf(mxz,v.z);
  }
#pragma unroll
  for (int off = 32; off >= 1; off >>= 1) {
    mnx=fminf(mnx,__shfl_xor(mnx,off)); mny=fminf(mny,__shfl_xor(mny,off)); mnz=fminf(mnz,__shfl_xor(mnz,off));
    mxx=fmaxf(mxx,__shfl_xor(mxx,off)); mxy=fmaxf(mxy,__shfl_xor(mxy,off)); mxz=fmaxf(mxz,__shfl_xor(mxz,off));
  }
  __shared__ float red[4][6];
  int wid = tid >> 6, lane = tid & 63;
  if (lane == 0) { red[wid][0]=mnx; red[wid][1]=mny; red[wid][2]=mnz;
                   red[wid][3]=mxx; red[wid][4]=mxy; red[wid][5]=mxz; }
  __syncthreads();
  mnx=fminf(fminf(red[0][0],red[1][0]),fminf(red[2][0],red[3][0]));
  mny=fminf(fminf(red[0][1],red[1][1]),fminf(red[2][1],red[3][1]));
  mnz=fminf(fminf(red[0][2],red[1][2]),fminf(red[2][2],red[3][2]));
  mxx=fmaxf(fmaxf(red[0][3],red[1][3]),fmaxf(red[2][3],red[3][3]));
  mxy=fmaxf(fmaxf(red[0][4],red[1][4]),fmaxf(red[2][4],red[3][4]));
  mxz=fmaxf(fmaxf(red[0][5],red[1][5]),fmaxf(red[2][5],red[3][5]));
  float cx=(mnx+mxx)*0.5f, cy=(mny+mxy)*0.5f, cz=(mnz+mxz)*0.5f;
#pragma unroll
  for (int i = 0; i < 8; ++i) {
    float dx=x[i]-cx, dy=y[i]-cy, dz=z[i]-cz;
    float n = sqrtf(((dx*dx) + dy*dy) + dz*dz);
    n = fmaxf(n, 1e-12f);
    float dxn = dx/n, dyn = dy/n, dzn = dz/n;
    float dotc = fminf(fmaxf(dyn, -0.99999990f), 0.99999990f);
    float half = acosf(dotc) * 0.5f;
    float an = sqrtf(dzn*dzn + dxn*dxn);
    an = fmaxf(an, 1e-12f);
    float axx = dzn/an, axz = (-dxn)/an;
    float s = sinf(half), w = cosf(half);
    bq[(size_t)bf*P_ + tid + i*256] = make_float4(w, axx*s, 0.f, axz*s);
    float qs = fmaf(x[i],x[i], fmaf(y[i],y[i], z[i]*z[i]));
    pts2[(size_t)bf*P_ + tid + i*256] = make_float4(x[i], y[i], z[i], qs);
  }
}

// ---------------- Kernel B: forward quaternions ----------------
__global__ __launch_bounds__(256) void kB_qfwd(const float4* __restrict__ bq,
                                               float4* __restrict__ qf) {
  int i = blockIdx.x*256 + threadIdx.x;   // over B*T*P
  int p = i & (P_-1);
  int t = (i >> 11) % T_;
  int b = i / (T_*P_);
  float4 s = bq[((size_t)(b*F_ + t))*P_ + p];       // frame t (src)
  float4 a = bq[((size_t)(b*F_ + t + 1))*P_ + p];   // frame t+1 (tgt)
  float aw=a.x, ax=a.y, ay=a.z, az=a.w;
  float bw=s.x, bx=-s.y, by=-s.z, bz=-s.w;          // conj
  float w  = ((aw*bw - ax*bx) - ay*by) - az*bz;
  float xo = ((aw*bx + ax*bw) + ay*bz) - az*by;
  float yo = ((aw*by - ax*bz) + ay*bw) + az*bx;
  float zo = ((aw*bz + ax*by) - ay*bx) + az*bw;
  float n = sqrtf(((w*w + xo*xo) + yo*yo) + zo*zo);
  n = fmaxf(n, 1e-12f);
  qf[i] = make_float4(w/n, xo/n, yo/n, zo/n);
}

// ---------------- Kernel C: top-40, quarter-wave rows, 4 waves/block ----------------
// trimmed mkkey: nd = (ps+c.w) - 2*dot == -((2*dot-ps)-c.w); 3-op ordf; hi/lo pack
__device__ __forceinline__ double mkkey(float4 c, u32 q,
                                        float px, float py, float pz, float ps) {
  float dot = fmaf(px, c.x, fmaf(py, c.y, pz*c.z));
  float nd  = fmaf(-2.f, dot, ps + c.w);   // ascending distance
  u32 u = __float_as_uint(nd);
  u32 ou = u ^ (((u32)((int)u >> 31)) | 0x80000000u);
  return __hiloint2double((int)((ou >> 16) | 0x40000000u), (int)((ou << 16) | q));
}
__device__ __forceinline__ u64 mkkey_u(float4 c, u32 q,
                                       float px, float py, float pz, float ps) {
  float dot = fmaf(px, c.x, fmaf(py, c.y, pz*c.z));
  float nd  = fmaf(-2.f, dot, ps + c.w);
  u32 u = __float_as_uint(nd);
  u32 ou = u ^ (((u32)((int)u >> 31)) | 0x80000000u);
  return ((u64)ou << 16) | q;
}

// one pop of the 4-rows-per-wave stream (each 16-lane quarter owns a row).
// LOU/LIX = last key THIS lane popped; maintained only on the cold refill path
// (a lane first exhausts after popping its entire initial queue in order, so
// its last-popped is initial acc[7] -> init LOU/LIX from that, no hot updates).
__device__ __forceinline__ void popstep(u32 (&OU)[8], u32 (&IX)[8],
                                        u32& LOU, u32& LIX, u32& CAP, int imod,
                                        int slot, const float4* __restrict__ pbase,
                                        float px, float py, float pz, float ps) {
  if (__any(OU[0] == SENT_OU)) {       // exact refill, cold (P ~ 0.4%/lane over 40 pops)
    bool need = (OU[0] == SENT_OU);
    u64 lastK = ((u64)LOU << 16) | LIX;
    u64 best = ~0ull;
    for (int j = 0; j < 128; ++j) {
      u32 q = (u32)(j*16 + slot);
      u64 kk = mkkey_u(pbase[q], q, px,py,pz,ps);
      if (kk > lastK && kk < best) best = kk;
    }
    if (need && best != ~0ull) {
      OU[0] = (u32)(best >> 16); IX[0] = (u32)(best & 0xffffu);
      LOU = OU[0]; LIX = IX[0];        // next-refill anchor for this lane
    }
  }
  u32 qmin = bfly16_min_u32(OU[0]);                  // all lanes get quarter min ou
  bool meq = (OU[0] == qmin);
  u32 tt   = meq ? IX[0] : 0xFFFFFFFFu;
  u32 widx = bfly16_min_u32(tt);                     // exact idx tie-break + broadcast
  bool iam = meq && (IX[0] == widx);
  CAP = (slot == imod) ? widx : CAP;
#pragma unroll
  for (int jj = 0; jj < 7; ++jj) {
    OU[jj] = iam ? OU[jj+1] : OU[jj];
    IX[jj] = iam ? IX[jj+1] : IX[jj];
  }
  OU[7] = iam ? SENT_OU : OU[7];
}

__global__ __launch_bounds__(256) void kC_select(const float4* __restrict__ pts2,
                                                 const float4* __restrict__ qf,
                                                 float* __restrict__ S) {
  int lane = threadIdx.x & 63;
  int wid  = threadIdx.x >> 6;         // wave within block (0..3)
  int slot = lane & 15;                // position within 16-lane quarter
  int quarter = lane >> 4;             // 0..3
  int gid = blockIdx.x * 16 + wid * 4; // first row of this wave
  int p0 = gid & (P_-1);               // 16 divides 2048 -> same tile across waves
  int bt = gid >> 11;                  // b*7 + t
  int t  = bt % T_;
  int b  = bt / T_;
  const float4* pbase = pts2 + (size_t)(b*F_ + t) * P_;

  int prow = p0 + quarter;             // this quarter's row
  float4 pw = pbase[prow];
  float px=pw.x, py=pw.y, pz=pw.z, ps=pw.w;

  // ---- sort phase: per lane 128 candidates (j*16+slot), keep sorted top-8 ----
  double acc[8];
  {
    double k0[8];
#pragma unroll
    for (int u = 0; u < 8; ++u) { float4 c = pbase[u*16 + slot];
      k0[u] = mkkey(c, (u32)(u*16 + slot), px,py,pz,ps); }
    sort8d(k0);
#pragma unroll
    for (int j = 0; j < 8; ++j) acc[j] = k0[j];
  }
#pragma unroll 2
  for (int batch = 1; batch < 16; ++batch) {
    int qb = batch*128 + slot;
    float4 c[8];
#pragma unroll
    for (int u = 0; u < 8; ++u) c[u] = pbase[qb + u*16];
    double k[8];
#pragma unroll
    for (int u = 0; u < 8; ++u) k[u] = mkkey(c[u], (u32)(qb + u*16), px,py,pz,ps);
    sort8d(k);
    low8(acc, k);
  }

  // unpack into register queue; refill anchor = last initial entry acc[7]
  u32 OU[8], IX[8];
#pragma unroll
  for (int j = 0; j < 8; ++j) {
    u64 bb = (u64)__double_as_longlong(acc[j]);
    OU[j] = (u32)(bb >> 16) & 0x3FFFFFFFu | ((u32)(bb >> 16) & 0xC0000000u ? 0u : 0u);
    OU[j] = (u32)((bb >> 16) & 0xFFFFFFFFull);   // keep 32 bits below exponent tag
    IX[j] = (u32)(bb & 0xffffu);
  }
  // strip the 0x4000 exponent tag bits that live above bit 46: (bb>>16) has the
  // tag at bits 46-47 -> bits 30-31 of OU. Remove them so OU is the pure ou32.
#pragma unroll
  for (int j = 0; j < 8; ++j) {
    u64 bb = (u64)__double_as_longlong(acc[j]);
    OU[j] = (u32)((bb & 0x0000FFFFFFFF0000ull) >> 16);
    IX[j] = (u32)(bb & 0xffffu);
  }
  u32 lou = OU[7], lix = IX[7];
  u32 cap1=0, cap2=0, cap3=0;

#pragma unroll 1
  for (int i = 0; i < 16; ++i)         // winners 0..15 -> cap1[slot==i]
    popstep(OU, IX, lou, lix, cap1, i, slot, pbase, px,py,pz,ps);
#pragma unroll 1
  for (int i = 0; i < 16; ++i)         // winners 16..31 -> cap2
    popstep(OU, IX, lou, lix, cap2, i, slot, pbase, px,py,pz,ps);
#pragma unroll 1
  for (int i = 0; i < 8; ++i)          // winners 32..39 -> cap3 (slots 0..7)
    popstep(OU, IX, lou, lix, cap3, i, slot, pbase, px,py,pz,ps);

  // ---- epilogue: geodesic sums ----
  int row = bt*P_ + prow;
  const float4* qbt = qf + (size_t)bt * P_;
  float4 qp = qf[row];

  float4 n; float d;
  n = qbt[cap1]; d = ((qp.x*n.x + qp.y*n.y) + qp.z*n.z) + qp.w*n.w;
  float g1 = 2.f * acosf(fminf(fabsf(d), 0.99999990f));
  n = qbt[cap2]; d = ((qp.x*n.x + qp.y*n.y) + qp.z*n.z) + qp.w*n.w;
  float g2 = 2.f * acosf(fminf(fabsf(d), 0.99999990f));
  n = qbt[cap3]; d = ((qp.x*n.x + qp.y*n.y) + qp.z*n.z) + qp.w*n.w;
  float g3 = (slot < 8) ? 2.f * acosf(fminf(fabsf(d), 0.99999990f)) : 0.f;

  float s40 = bfly16_sum_f32(g1 + g2 + g3);
  float s15 = bfly16_sum_f32((slot < 15) ? g1 : 0.f);
  float s5  = bfly16_sum_f32((slot < 5)  ? g1 : 0.f);

  if (slot == 0) {
    S[0*ROWS + row] = s5  / 5.f;
    S[1*ROWS + row] = s15 / 15.f;
    S[2*ROWS + row] = s40 / 40.f;
  }
}

// ---------------- Kernel E: mean over t, median, output (all 3 scales, 1 block) ----
__global__ __launch_bounds__(1024) void kE_final(const float* __restrict__ S,
                                                 float* __restrict__ out) {
  int tid = threadIdx.x;
  __shared__ float srt[3][4096];
  float m[3][4];
#pragma unroll
  for (int k = 0; k < 3; ++k) {
    const float* Sk = S + (size_t)k * ROWS;
#pragma unroll
    for (int u = 0; u < 4; ++u) {
      int j = tid + u*1024;            // j = b*2048 + p
      int b = j >> 11, p = j & 2047;
      float acc = 0.f;
#pragma unroll
      for (int t = 0; t < 7; ++t) acc += Sk[(b*7 + t)*2048 + p];
      m[k][u] = acc / 7.f;
      srt[k][j] = m[k][u];
    }
  }
  __syncthreads();
  for (int size = 2; size <= 4096; size <<= 1) {
    for (int stride = size >> 1; stride > 0; stride >>= 1) {
      for (int c = tid; c < 2048; c += 1024) {
        int i = 2*c - (c & (stride - 1));
        int j = i + stride;
        bool up = ((i & size) == 0);
#pragma unroll
        for (int k = 0; k < 3; ++k) {
          float a = srt[k][i], bb = srt[k][j];
          if ((a > bb) == up) { srt[k][i] = bb; srt[k][j] = a; }
        }
      }
      __syncthreads();
    }
  }
#pragma unroll
  for (int k = 0; k < 3; ++k) {
    float scale = fmaxf(srt[k][2047], 1e-6f);  // lower median of 4096
    bool pos = srt[k][4095] > 0.f;
#pragma unroll
    for (int u = 0; u < 4; ++u) {
      int j = tid + u*1024;
      int b = j >> 11, p = j & 2047;
      float r = pos ? expf(-m[k][u]/scale) : 1.f;
      float* ob = out + ((size_t)(b*3 + k)*8)*2048 + p;
#pragma unroll
      for (int f = 0; f < 8; ++f) ob[f*2048] = r;
    }
  }
}

extern "C" void kernel_launch(void* const* d_in, const int* in_sizes, int n_in,
                              void* d_out, int out_size, void* d_ws, size_t ws_size,
                              hipStream_t stream) {
  (void)in_sizes; (void)n_in; (void)out_size; (void)ws_size;
  const float4* pts = (const float4*)d_in[0];
  float* ws = (float*)d_ws;
  float4* bq   = (float4*)ws;                     // B*F*P*4   = 131072 floats
  float4* qfw  = (float4*)(ws + 131072);          // B*T*P*4   = 114688 floats
  float*  S    = ws + 131072 + 114688;            // 3*ROWS    =  86016 floats
  float4* pts2 = (float4*)(ws + 131072 + 114688 + 86016);  // B*F*P*4 = 131072 floats
  float*  out = (float*)d_out;

  hipLaunchKernelGGL(kA_bearing, dim3(B_*F_), dim3(256), 0, stream, pts, bq, pts2);
  hipLaunchKernelGGL(kB_qfwd,    dim3(ROWS/256), dim3(256), 0, stream, bq, qfw);
  hipLaunchKernelGGL(kC_select,  dim3(ROWS/16), dim3(256), 0, stream, pts2, qfw, S);
  hipLaunchKernelGGL(kE_final,   dim3(1), dim3(1024), 0, stream, S, out);
}

// Round 10
// 129.532 us; speedup vs baseline: 1.6355x; 1.3086x over previous
//
#include <hip/hip_runtime.h>
#include <math.h>

typedef unsigned long long u64;
typedef unsigned int u32;

#define B_ 2
#define F_ 8
#define P_ 2048
#define T_ 7                   // F-1
#define ROWS (B_*T_*P_)        // 28672
#define SENT_OU 0xFFFFFFFFu

// ---- keys as positive-normal doubles: bit pattern 0x4000.. | ou<<16 | idx ----
// positive doubles: IEEE ordering == integer ordering -> CE = v_min_f64+v_max_f64
// (r8 measured: u64 integer CE is 1.4x MORE VALU cycles; f64 CE is the winner)
#define CED(arr,a,b) do { double _x=arr[a], _y=arr[b]; arr[a]=fmin(_x,_y); arr[b]=fmax(_x,_y); } while(0)

// Batcher odd-even mergesort, 8 elements, 19 comparators
__device__ __forceinline__ void sort8d(double* k) {
  CED(k,0,1); CED(k,2,3); CED(k,4,5); CED(k,6,7);
  CED(k,0,2); CED(k,1,3); CED(k,4,6); CED(k,5,7);
  CED(k,1,2); CED(k,5,6);
  CED(k,0,4); CED(k,1,5); CED(k,2,6); CED(k,3,7);
  CED(k,2,4); CED(k,3,5);
  CED(k,1,2); CED(k,3,4); CED(k,5,6);
}

// A,B sorted ascending -> A = lowest 8 of the 16, sorted
__device__ __forceinline__ void low8(double* A, const double* Bv) {
#pragma unroll
  for (int i = 0; i < 8; ++i) A[i] = fmin(A[i], Bv[7-i]);   // bitonic
#pragma unroll
  for (int st = 4; st >= 1; st >>= 1) {
#pragma unroll
    for (int i = 0; i < 8; ++i) {
      if ((i & st) == 0) { CED(A, i, i + st); }
    }
  }
}

// ---- quarter(16-lane)-local butterfly reductions via DPP: result in ALL lanes ----
__device__ __forceinline__ u32 bfly16_min_u32(u32 x) {
  u32 t;
  t = (u32)__builtin_amdgcn_update_dpp((int)x,(int)x,0x0B1,0xF,0xF,false); x = t<x?t:x;
  t = (u32)__builtin_amdgcn_update_dpp((int)x,(int)x,0x04E,0xF,0xF,false); x = t<x?t:x;
  t = (u32)__builtin_amdgcn_update_dpp((int)x,(int)x,0x141,0xF,0xF,false); x = t<x?t:x;
  t = (u32)__builtin_amdgcn_update_dpp((int)x,(int)x,0x140,0xF,0xF,false); x = t<x?t:x;
  return x;
}
__device__ __forceinline__ float bfly16_sum_f32(float x) {
  float t;
  t = __uint_as_float((u32)__builtin_amdgcn_update_dpp((int)__float_as_uint(x),(int)__float_as_uint(x),0x0B1,0xF,0xF,false)); x += t;
  t = __uint_as_float((u32)__builtin_amdgcn_update_dpp((int)__float_as_uint(x),(int)__float_as_uint(x),0x04E,0xF,0xF,false)); x += t;
  t = __uint_as_float((u32)__builtin_amdgcn_update_dpp((int)__float_as_uint(x),(int)__float_as_uint(x),0x141,0xF,0xF,false)); x += t;
  t = __uint_as_float((u32)__builtin_amdgcn_update_dpp((int)__float_as_uint(x),(int)__float_as_uint(x),0x140,0xF,0xF,false)); x += t;
  return x;
}

// ---------------- Kernel A: bearing quaternions + |q|^2 prepack ----------------
__global__ __launch_bounds__(256) void kA_bearing(const float4* __restrict__ pts,
                                                  float4* __restrict__ bq,
                                                  float4* __restrict__ pts2) {
  int bf = blockIdx.x;                // b*F + f
  const float4* base = pts + (size_t)bf * P_;
  int tid = threadIdx.x;
  float x[8], y[8], z[8];
  float mnx =  INFINITY, mny =  INFINITY, mnz =  INFINITY;
  float mxx = -INFINITY, mxy = -INFINITY, mxz = -INFINITY;
#pragma unroll
  for (int i = 0; i < 8; ++i) {
    float4 v = base[tid + i*256];
    x[i]=v.x; y[i]=v.y; z[i]=v.z;
    mnx=fminf(mnx,v.x); mny=fminf(mny,v.y); mnz=fminf(mnz,v.z);
    mxx=fmaxf(mxx,v.x); mxy=fmaxf(mxy,v.y); mxz=fmaxf(mxz,v.z);
  }
#pragma unroll
  for (int off = 32; off >= 1; off >>= 1) {
    mnx=fminf(mnx,__shfl_xor(mnx,off)); mny=fminf(mny,__shfl_xor(mny,off)); mnz=fminf(mnz,__shfl_xor(mnz,off));
    mxx=fmaxf(mxx,__shfl_xor(mxx,off)); mxy=fmaxf(mxy,__shfl_xor(mxy,off)); mxz=fmaxf(mxz,__shfl_xor(mxz,off));
  }
  __shared__ float red[4][6];
  int wid = tid >> 6, lane = tid & 63;
  if (lane == 0) { red[wid][0]=mnx; red[wid][1]=mny; red[wid][2]=mnz;
                   red[wid][3]=mxx; red[wid][4]=mxy; red[wid][5]=mxz; }
  __syncthreads();
  mnx=fminf(fminf(red[0][0],red[1][0]),fminf(red[2][0],red[3][0]));
  mny=fminf(fminf(red[0][1],red[1][1]),fminf(red[2][1],red[3][1]));
  mnz=fminf(fminf(red[0][2],red[1][2]),fminf(red[2][2],red[3][2]));
  mxx=fmaxf(fmaxf(red[0][3],red[1][3]),fmaxf(red[2][3],red[3][3]));
  mxy=fmaxf(fmaxf(red[0][4],red[1][4]),fmaxf(red[2][4],red[3][4]));
  mxz=fmaxf(fmaxf(red[0][5],red[1][5]),fmaxf(red[2][5],red[3][5]));
  float cx=(mnx+mxx)*0.5f, cy=(mny+mxy)*0.5f, cz=(mnz+mxz)*0.5f;
#pragma unroll
  for (int i = 0; i < 8; ++i) {
    float dx=x[i]-cx, dy=y[i]-cy, dz=z[i]-cz;
    float n = sqrtf(((dx*dx) + dy*dy) + dz*dz);
    n = fmaxf(n, 1e-12f);
    float dxn = dx/n, dyn = dy/n, dzn = dz/n;
    float dotc = fminf(fmaxf(dyn, -0.99999990f), 0.99999990f);
    float half = acosf(dotc) * 0.5f;
    float an = sqrtf(dzn*dzn + dxn*dxn);
    an = fmaxf(an, 1e-12f);
    float axx = dzn/an, axz = (-dxn)/an;
    float s = sinf(half), w = cosf(half);
    bq[(size_t)bf*P_ + tid + i*256] = make_float4(w, axx*s, 0.f, axz*s);
    float qs = fmaf(x[i],x[i], fmaf(y[i],y[i], z[i]*z[i]));
    pts2[(size_t)bf*P_ + tid + i*256] = make_float4(x[i], y[i], z[i], qs);
  }
}

// ---------------- Kernel B: forward quaternions ----------------
__global__ __launch_bounds__(256) void kB_qfwd(const float4* __restrict__ bq,
                                               float4* __restrict__ qf) {
  int i = blockIdx.x*256 + threadIdx.x;   // over B*T*P
  int p = i & (P_-1);
  int t = (i >> 11) % T_;
  int b = i / (T_*P_);
  float4 s = bq[((size_t)(b*F_ + t))*P_ + p];       // frame t (src)
  float4 a = bq[((size_t)(b*F_ + t + 1))*P_ + p];   // frame t+1 (tgt)
  float aw=a.x, ax=a.y, ay=a.z, az=a.w;
  float bw=s.x, bx=-s.y, by=-s.z, bz=-s.w;          // conj
  float w  = ((aw*bw - ax*bx) - ay*by) - az*bz;
  float xo = ((aw*bx + ax*bw) + ay*bz) - az*by;
  float yo = ((aw*by - ax*bz) + ay*bw) + az*bx;
  float zo = ((aw*bz + ax*by) - ay*bx) + az*bw;
  float n = sqrtf(((w*w + xo*xo) + yo*yo) + zo*zo);
  n = fmaxf(n, 1e-12f);
  qf[i] = make_float4(w/n, xo/n, yo/n, zo/n);
}

// ---------------- Kernel C: top-40, quarter-wave rows, 4 waves/block ----------------
// trimmed mkkey: nd = (ps+c.w) - 2*dot; 3-op ordered-float; hi/lo f64 pack
__device__ __forceinline__ double mkkey(float4 c, u32 q,
                                        float px, float py, float pz, float ps) {
  float dot = fmaf(px, c.x, fmaf(py, c.y, pz*c.z));
  float nd  = fmaf(-2.f, dot, ps + c.w);   // ascending distance
  u32 u = __float_as_uint(nd);
  u32 ou = u ^ (((u32)((int)u >> 31)) | 0x80000000u);
  return __hiloint2double((int)((ou >> 16) | 0x40000000u), (int)((ou << 16) | q));
}
__device__ __forceinline__ u64 mkkey_u(float4 c, u32 q,
                                       float px, float py, float pz, float ps) {
  float dot = fmaf(px, c.x, fmaf(py, c.y, pz*c.z));
  float nd  = fmaf(-2.f, dot, ps + c.w);
  u32 u = __float_as_uint(nd);
  u32 ou = u ^ (((u32)((int)u >> 31)) | 0x80000000u);
  return ((u64)ou << 16) | q;
}

// one pop of the 4-rows-per-wave stream (each 16-lane quarter owns a row).
// LOU/LIX = last key THIS lane popped; maintained only on the cold refill path
// (a lane first exhausts after popping its entire initial queue in order, so
// its last-popped is initial acc[7] -> init LOU/LIX from that, no hot updates).
__device__ __forceinline__ void popstep(u32 (&OU)[8], u32 (&IX)[8],
                                        u32& LOU, u32& LIX, u32& CAP, int imod,
                                        int slot, const float4* __restrict__ pbase,
                                        float px, float py, float pz, float ps) {
  if (__any(OU[0] == SENT_OU)) {       // exact refill, cold (P ~ 0.4%/wave over 40 pops)
    bool need = (OU[0] == SENT_OU);
    u64 lastK = ((u64)LOU << 16) | LIX;
    u64 best = ~0ull;
    for (int j = 0; j < 128; ++j) {
      u32 q = (u32)(j*16 + slot);
      u64 kk = mkkey_u(pbase[q], q, px,py,pz,ps);
      if (kk > lastK && kk < best) best = kk;
    }
    if (need && best != ~0ull) {
      OU[0] = (u32)(best >> 16); IX[0] = (u32)(best & 0xffffu);
      LOU = OU[0]; LIX = IX[0];        // next-refill anchor for this lane
    }
  }
  u32 qmin = bfly16_min_u32(OU[0]);                  // all lanes get quarter min ou
  bool meq = (OU[0] == qmin);
  u32 tt   = meq ? IX[0] : 0xFFFFFFFFu;
  u32 widx = bfly16_min_u32(tt);                     // exact idx tie-break + broadcast
  bool iam = meq && (IX[0] == widx);
  CAP = (slot == imod) ? widx : CAP;
#pragma unroll
  for (int jj = 0; jj < 7; ++jj) {
    OU[jj] = iam ? OU[jj+1] : OU[jj];
    IX[jj] = iam ? IX[jj+1] : IX[jj];
  }
  OU[7] = iam ? SENT_OU : OU[7];
}

__global__ __launch_bounds__(256) void kC_select(const float4* __restrict__ pts2,
                                                 const float4* __restrict__ qf,
                                                 float* __restrict__ S) {
  int lane = threadIdx.x & 63;
  int wid  = threadIdx.x >> 6;         // wave within block (0..3)
  int slot = lane & 15;                // position within 16-lane quarter
  int quarter = lane >> 4;             // 0..3
  int gid = blockIdx.x * 16 + wid * 4; // first row of this wave
  int p0 = gid & (P_-1);               // 16 divides 2048 -> same tile across waves
  int bt = gid >> 11;                  // b*7 + t
  int t  = bt % T_;
  int b  = bt / T_;
  const float4* pbase = pts2 + (size_t)(b*F_ + t) * P_;

  int prow = p0 + quarter;             // this quarter's row
  float4 pw = pbase[prow];
  float px=pw.x, py=pw.y, pz=pw.z, ps=pw.w;

  // ---- sort phase: per lane 128 candidates (j*16+slot), keep sorted top-8 ----
  double acc[8];
  {
    double k0[8];
#pragma unroll
    for (int u = 0; u < 8; ++u) { float4 c = pbase[u*16 + slot];
      k0[u] = mkkey(c, (u32)(u*16 + slot), px,py,pz,ps); }
    sort8d(k0);
#pragma unroll
    for (int j = 0; j < 8; ++j) acc[j] = k0[j];
  }
#pragma unroll 2
  for (int batch = 1; batch < 16; ++batch) {
    int qb = batch*128 + slot;
    float4 c[8];
#pragma unroll
    for (int u = 0; u < 8; ++u) c[u] = pbase[qb + u*16];
    double k[8];
#pragma unroll
    for (int u = 0; u < 8; ++u) k[u] = mkkey(c[u], (u32)(qb + u*16), px,py,pz,ps);
    sort8d(k);
    low8(acc, k);
  }

  // unpack into register queue (strip f64 exponent tag: bits 46-47 of the u64);
  // refill anchor = last initial entry acc[7]
  u32 OU[8], IX[8];
#pragma unroll
  for (int j = 0; j < 8; ++j) {
    u64 bb = (u64)__double_as_longlong(acc[j]);
    OU[j] = (u32)((bb & 0x0000FFFFFFFF0000ull) >> 16);
    IX[j] = (u32)(bb & 0xffffu);
  }
  u32 lou = OU[7], lix = IX[7];
  u32 cap1=0, cap2=0, cap3=0;

#pragma unroll 1
  for (int i = 0; i < 16; ++i)         // winners 0..15 -> cap1[slot==i]
    popstep(OU, IX, lou, lix, cap1, i, slot, pbase, px,py,pz,ps);
#pragma unroll 1
  for (int i = 0; i < 16; ++i)         // winners 16..31 -> cap2
    popstep(OU, IX, lou, lix, cap2, i, slot, pbase, px,py,pz,ps);
#pragma unroll 1
  for (int i = 0; i < 8; ++i)          // winners 32..39 -> cap3 (slots 0..7)
    popstep(OU, IX, lou, lix, cap3, i, slot, pbase, px,py,pz,ps);

  // ---- epilogue: geodesic sums ----
  int row = bt*P_ + prow;
  const float4* qbt = qf + (size_t)bt * P_;
  float4 qp = qf[row];

  float4 n; float d;
  n = qbt[cap1]; d = ((qp.x*n.x + qp.y*n.y) + qp.z*n.z) + qp.w*n.w;
  float g1 = 2.f * acosf(fminf(fabsf(d), 0.99999990f));
  n = qbt[cap2]; d = ((qp.x*n.x + qp.y*n.y) + qp.z*n.z) + qp.w*n.w;
  float g2 = 2.f * acosf(fminf(fabsf(d), 0.99999990f));
  n = qbt[cap3]; d = ((qp.x*n.x + qp.y*n.y) + qp.z*n.z) + qp.w*n.w;
  float g3 = (slot < 8) ? 2.f * acosf(fminf(fabsf(d), 0.99999990f)) : 0.f;

  float s40 = bfly16_sum_f32(g1 + g2 + g3);
  float s15 = bfly16_sum_f32((slot < 15) ? g1 : 0.f);
  float s5  = bfly16_sum_f32((slot < 5)  ? g1 : 0.f);

  if (slot == 0) {
    S[0*ROWS + row] = s5  / 5.f;
    S[1*ROWS + row] = s15 / 15.f;
    S[2*ROWS + row] = s40 / 40.f;
  }
}

// ---------------- Kernel E: mean over t, median, output (1 block per scale) ----
__global__ __launch_bounds__(1024) void kE_final(const float* __restrict__ S,
                                                 float* __restrict__ out) {
  int k = blockIdx.x;                  // scale index 0..2
  int tid = threadIdx.x;
  __shared__ float srt[4096];
  const float* Sk = S + (size_t)k * ROWS;
  float m[4];
#pragma unroll
  for (int u = 0; u < 4; ++u) {
    int j = tid + u*1024;              // j = b*2048 + p
    int b = j >> 11, p = j & 2047;
    float acc = 0.f;
#pragma unroll
    for (int t = 0; t < 7; ++t) acc += Sk[(b*7 + t)*2048 + p];
    m[u] = acc / 7.f;
    srt[j] = m[u];
  }
  __syncthreads();
  for (int size = 2; size <= 4096; size <<= 1) {
    for (int stride = size >> 1; stride > 0; stride >>= 1) {
      for (int c = tid; c < 2048; c += 1024) {
        int i = 2*c - (c & (stride - 1));
        int j = i + stride;
        bool up = ((i & size) == 0);
        float a = srt[i], bb = srt[j];
        if ((a > bb) == up) { srt[i] = bb; srt[j] = a; }
      }
      __syncthreads();
    }
  }
  float scale = fmaxf(srt[2047], 1e-6f);   // lower median of 4096
  bool pos = srt[4095] > 0.f;
#pragma unroll
  for (int u = 0; u < 4; ++u) {
    int j = tid + u*1024;
    int b = j >> 11, p = j & 2047;
    float r = pos ? expf(-m[u]/scale) : 1.f;
    float* ob = out + ((size_t)(b*3 + k)*8)*2048 + p;
#pragma unroll
    for (int f = 0; f < 8; ++f) ob[f*2048] = r;
  }
}

extern "C" void kernel_launch(void* const* d_in, const int* in_sizes, int n_in,
                              void* d_out, int out_size, void* d_ws, size_t ws_size,
                              hipStream_t stream) {
  (void)in_sizes; (void)n_in; (void)out_size; (void)ws_size;
  const float4* pts = (const float4*)d_in[0];
  float* ws = (float*)d_ws;
  float4* bq   = (float4*)ws;                     // B*F*P*4   = 131072 floats
  float4* qfw  = (float4*)(ws + 131072);          // B*T*P*4   = 114688 floats
  float*  S    = ws + 131072 + 114688;            // 3*ROWS    =  86016 floats
  float4* pts2 = (float4*)(ws + 131072 + 114688 + 86016);  // B*F*P*4 = 131072 floats
  float*  out = (float*)d_out;

  hipLaunchKernelGGL(kA_bearing, dim3(B_*F_), dim3(256), 0, stream, pts, bq, pts2);
  hipLaunchKernelGGL(kB_qfwd,    dim3(ROWS/256), dim3(256), 0, stream, bq, qfw);
  hipLaunchKernelGGL(kC_select,  dim3(ROWS/16), dim3(256), 0, stream, pts2, qfw, S);
  hipLaunchKernelGGL(kE_final,   dim3(3), dim3(1024), 0, stream, S, out);
}

// Round 11
// 125.563 us; speedup vs baseline: 1.6872x; 1.0316x over previous
//
#include <hip/hip_runtime.h>
#include <math.h>

typedef unsigned long long u64;
typedef unsigned int u32;

#define B_ 2
#define F_ 8
#define P_ 2048
#define T_ 7                   // F-1
#define ROWS (B_*T_*P_)        // 28672
#define SENT_OU 0xFFFFFFFFu

// ---- keys as positive-normal doubles: bit pattern 0x4000.. | ou<<16 | idx ----
// positive doubles: IEEE ordering == integer ordering -> CE = v_min_f64+v_max_f64
// (r8 measured: u64 integer CE is 1.4x MORE VALU cycles; f64 CE is the winner)
#define CED(arr,a,b) do { double _x=arr[a], _y=arr[b]; arr[a]=fmin(_x,_y); arr[b]=fmax(_x,_y); } while(0)

// Batcher odd-even mergesort, 8 elements, 19 comparators
__device__ __forceinline__ void sort8d(double* k) {
  CED(k,0,1); CED(k,2,3); CED(k,4,5); CED(k,6,7);
  CED(k,0,2); CED(k,1,3); CED(k,4,6); CED(k,5,7);
  CED(k,1,2); CED(k,5,6);
  CED(k,0,4); CED(k,1,5); CED(k,2,6); CED(k,3,7);
  CED(k,2,4); CED(k,3,5);
  CED(k,1,2); CED(k,3,4); CED(k,5,6);
}

// A,B sorted ascending -> A = lowest 8 of the 16, sorted
__device__ __forceinline__ void low8(double* A, const double* Bv) {
#pragma unroll
  for (int i = 0; i < 8; ++i) A[i] = fmin(A[i], Bv[7-i]);   // bitonic
#pragma unroll
  for (int st = 4; st >= 1; st >>= 1) {
#pragma unroll
    for (int i = 0; i < 8; ++i) {
      if ((i & st) == 0) { CED(A, i, i + st); }
    }
  }
}

// ---- quarter(16-lane)-local butterfly reductions via DPP: result in ALL lanes ----
__device__ __forceinline__ u32 bfly16_min_u32(u32 x) {
  u32 t;
  t = (u32)__builtin_amdgcn_update_dpp((int)x,(int)x,0x0B1,0xF,0xF,false); x = t<x?t:x;
  t = (u32)__builtin_amdgcn_update_dpp((int)x,(int)x,0x04E,0xF,0xF,false); x = t<x?t:x;
  t = (u32)__builtin_amdgcn_update_dpp((int)x,(int)x,0x141,0xF,0xF,false); x = t<x?t:x;
  t = (u32)__builtin_amdgcn_update_dpp((int)x,(int)x,0x140,0xF,0xF,false); x = t<x?t:x;
  return x;
}
__device__ __forceinline__ float bfly16_sum_f32(float x) {
  float t;
  t = __uint_as_float((u32)__builtin_amdgcn_update_dpp((int)__float_as_uint(x),(int)__float_as_uint(x),0x0B1,0xF,0xF,false)); x += t;
  t = __uint_as_float((u32)__builtin_amdgcn_update_dpp((int)__float_as_uint(x),(int)__float_as_uint(x),0x04E,0xF,0xF,false)); x += t;
  t = __uint_as_float((u32)__builtin_amdgcn_update_dpp((int)__float_as_uint(x),(int)__float_as_uint(x),0x141,0xF,0xF,false)); x += t;
  t = __uint_as_float((u32)__builtin_amdgcn_update_dpp((int)__float_as_uint(x),(int)__float_as_uint(x),0x140,0xF,0xF,false)); x += t;
  return x;
}

// ---------------- Kernel A: bearing quaternions + |q|^2 prepack ----------------
__global__ __launch_bounds__(256) void kA_bearing(const float4* __restrict__ pts,
                                                  float4* __restrict__ bq,
                                                  float4* __restrict__ pts2) {
  int bf = blockIdx.x;                // b*F + f
  const float4* base = pts + (size_t)bf * P_;
  int tid = threadIdx.x;
  float x[8], y[8], z[8];
  float mnx =  INFINITY, mny =  INFINITY, mnz =  INFINITY;
  float mxx = -INFINITY, mxy = -INFINITY, mxz = -INFINITY;
#pragma unroll
  for (int i = 0; i < 8; ++i) {
    float4 v = base[tid + i*256];
    x[i]=v.x; y[i]=v.y; z[i]=v.z;
    mnx=fminf(mnx,v.x); mny=fminf(mny,v.y); mnz=fminf(mnz,v.z);
    mxx=fmaxf(mxx,v.x); mxy=fmaxf(mxy,v.y); mxz=fmaxf(mxz,v.z);
  }
#pragma unroll
  for (int off = 32; off >= 1; off >>= 1) {
    mnx=fminf(mnx,__shfl_xor(mnx,off)); mny=fminf(mny,__shfl_xor(mny,off)); mnz=fminf(mnz,__shfl_xor(mnz,off));
    mxx=fmaxf(mxx,__shfl_xor(mxx,off)); mxy=fmaxf(mxy,__shfl_xor(mxy,off)); mxz=fmaxf(mxz,__shfl_xor(mxz,off));
  }
  __shared__ float red[4][6];
  int wid = tid >> 6, lane = tid & 63;
  if (lane == 0) { red[wid][0]=mnx; red[wid][1]=mny; red[wid][2]=mnz;
                   red[wid][3]=mxx; red[wid][4]=mxy; red[wid][5]=mxz; }
  __syncthreads();
  mnx=fminf(fminf(red[0][0],red[1][0]),fminf(red[2][0],red[3][0]));
  mny=fminf(fminf(red[0][1],red[1][1]),fminf(red[2][1],red[3][1]));
  mnz=fminf(fminf(red[0][2],red[1][2]),fminf(red[2][2],red[3][2]));
  mxx=fmaxf(fmaxf(red[0][3],red[1][3]),fmaxf(red[2][3],red[3][3]));
  mxy=fmaxf(fmaxf(red[0][4],red[1][4]),fmaxf(red[2][4],red[3][4]));
  mxz=fmaxf(fmaxf(red[0][5],red[1][5]),fmaxf(red[2][5],red[3][5]));
  float cx=(mnx+mxx)*0.5f, cy=(mny+mxy)*0.5f, cz=(mnz+mxz)*0.5f;
#pragma unroll
  for (int i = 0; i < 8; ++i) {
    float dx=x[i]-cx, dy=y[i]-cy, dz=z[i]-cz;
    float n = sqrtf(((dx*dx) + dy*dy) + dz*dz);
    n = fmaxf(n, 1e-12f);
    float dxn = dx/n, dyn = dy/n, dzn = dz/n;
    float dotc = fminf(fmaxf(dyn, -0.99999990f), 0.99999990f);
    float half = acosf(dotc) * 0.5f;
    float an = sqrtf(dzn*dzn + dxn*dxn);
    an = fmaxf(an, 1e-12f);
    float axx = dzn/an, axz = (-dxn)/an;
    float s = sinf(half), w = cosf(half);
    bq[(size_t)bf*P_ + tid + i*256] = make_float4(w, axx*s, 0.f, axz*s);
    float qs = fmaf(x[i],x[i], fmaf(y[i],y[i], z[i]*z[i]));
    pts2[(size_t)bf*P_ + tid + i*256] = make_float4(x[i], y[i], z[i], qs);
  }
}

// ---------------- Kernel B: forward quaternions ----------------
__global__ __launch_bounds__(256) void kB_qfwd(const float4* __restrict__ bq,
                                               float4* __restrict__ qf) {
  int i = blockIdx.x*256 + threadIdx.x;   // over B*T*P
  int p = i & (P_-1);
  int t = (i >> 11) % T_;
  int b = i / (T_*P_);
  float4 s = bq[((size_t)(b*F_ + t))*P_ + p];       // frame t (src)
  float4 a = bq[((size_t)(b*F_ + t + 1))*P_ + p];   // frame t+1 (tgt)
  float aw=a.x, ax=a.y, ay=a.z, az=a.w;
  float bw=s.x, bx=-s.y, by=-s.z, bz=-s.w;          // conj
  float w  = ((aw*bw - ax*bx) - ay*by) - az*bz;
  float xo = ((aw*bx + ax*bw) + ay*bz) - az*by;
  float yo = ((aw*by - ax*bz) + ay*bw) + az*bx;
  float zo = ((aw*bz + ax*by) - ay*bx) + az*bw;
  float n = sqrtf(((w*w + xo*xo) + yo*yo) + zo*zo);
  n = fmaxf(n, 1e-12f);
  qf[i] = make_float4(w/n, xo/n, yo/n, zo/n);
}

// ---------------- Kernel C: top-40, quarter-wave rows, 4 waves/block ----------------
// trimmed mkkey: nd = (ps+c.w) - 2*dot; 3-op ordered-float; hi/lo f64 pack
__device__ __forceinline__ double mkkey(float4 c, u32 q,
                                        float px, float py, float pz, float ps) {
  float dot = fmaf(px, c.x, fmaf(py, c.y, pz*c.z));
  float nd  = fmaf(-2.f, dot, ps + c.w);   // ascending distance
  u32 u = __float_as_uint(nd);
  u32 ou = u ^ (((u32)((int)u >> 31)) | 0x80000000u);
  return __hiloint2double((int)((ou >> 16) | 0x40000000u), (int)((ou << 16) | q));
}
__device__ __forceinline__ u64 mkkey_u(float4 c, u32 q,
                                       float px, float py, float pz, float ps) {
  float dot = fmaf(px, c.x, fmaf(py, c.y, pz*c.z));
  float nd  = fmaf(-2.f, dot, ps + c.w);
  u32 u = __float_as_uint(nd);
  u32 ou = u ^ (((u32)((int)u >> 31)) | 0x80000000u);
  return ((u64)ou << 16) | q;
}

// one pop of the 4-rows-per-wave stream (each 16-lane quarter owns a row).
// LOU/LIX = last key THIS lane popped; maintained only on the cold refill path
// (a lane first exhausts after popping its entire initial queue in order, so
// its last-popped is initial acc[7] -> init LOU/LIX from that, no hot updates).
__device__ __forceinline__ void popstep(u32 (&OU)[8], u32 (&IX)[8],
                                        u32& LOU, u32& LIX, u32& CAP, int imod,
                                        int slot, const float4* __restrict__ pbase,
                                        float px, float py, float pz, float ps) {
  if (__any(OU[0] == SENT_OU)) {       // exact refill, cold (P ~ 0.4%/wave over 40 pops)
    bool need = (OU[0] == SENT_OU);
    u64 lastK = ((u64)LOU << 16) | LIX;
    u64 best = ~0ull;
    for (int j = 0; j < 128; ++j) {
      u32 q = (u32)(j*16 + slot);
      u64 kk = mkkey_u(pbase[q], q, px,py,pz,ps);
      if (kk > lastK && kk < best) best = kk;
    }
    if (need && best != ~0ull) {
      OU[0] = (u32)(best >> 16); IX[0] = (u32)(best & 0xffffu);
      LOU = OU[0]; LIX = IX[0];        // next-refill anchor for this lane
    }
  }
  u32 qmin = bfly16_min_u32(OU[0]);                  // all lanes get quarter min ou
  bool meq = (OU[0] == qmin);
  u32 tt   = meq ? IX[0] : 0xFFFFFFFFu;
  u32 widx = bfly16_min_u32(tt);                     // exact idx tie-break + broadcast
  bool iam = meq && (IX[0] == widx);
  CAP = (slot == imod) ? widx : CAP;
#pragma unroll
  for (int jj = 0; jj < 7; ++jj) {
    OU[jj] = iam ? OU[jj+1] : OU[jj];
    IX[jj] = iam ? IX[jj+1] : IX[jj];
  }
  OU[7] = iam ? SENT_OU : OU[7];
}

__global__ __launch_bounds__(256, 2) void kC_select(const float4* __restrict__ pts2,
                                                    const float4* __restrict__ qf,
                                                    float* __restrict__ S) {
  int lane = threadIdx.x & 63;
  int wid  = threadIdx.x >> 6;         // wave within block (0..3)
  int slot = lane & 15;                // position within 16-lane quarter
  int quarter = lane >> 4;             // 0..3
  int gid = blockIdx.x * 16 + wid * 4; // first row of this wave
  int p0 = gid & (P_-1);               // 16 divides 2048 -> same tile across waves
  int bt = gid >> 11;                  // b*7 + t
  int t  = bt % T_;
  int b  = bt / T_;
  const float4* pbase = pts2 + (size_t)(b*F_ + t) * P_;

  int prow = p0 + quarter;             // this quarter's row
  float4 pw = pbase[prow];
  float px=pw.x, py=pw.y, pz=pw.z, ps=pw.w;

  // ---- sort phase: 128 candidates/lane, double-buffered loads (cA/cB) so the
  // next batch's 8 float4 are ALWAYS in flight while the current batch sorts.
  // (r10 post-mortem: VGPR=32 allocator serialized loads -> latency-bound.)
  double acc[8];
  float4 cA[8], cB[8];
#pragma unroll
  for (int u = 0; u < 8; ++u) cA[u] = pbase[u*16 + slot];            // batch 0
#pragma unroll
  for (int u = 0; u < 8; ++u) cB[u] = pbase[128 + u*16 + slot];      // batch 1
  {
    double k0[8];
#pragma unroll
    for (int u = 0; u < 8; ++u) k0[u] = mkkey(cA[u], (u32)(u*16 + slot), px,py,pz,ps);
#pragma unroll
    for (int u = 0; u < 8; ++u) cA[u] = pbase[256 + u*16 + slot];    // prefetch batch 2
    sort8d(k0);
#pragma unroll
    for (int j = 0; j < 8; ++j) acc[j] = k0[j];
  }
#pragma unroll
  for (int pair = 0; pair < 7; ++pair) {
    // process cB = batch 2*pair+1 ; prefetch cB <- batch 2*pair+3
    {
      int qb = (2*pair + 1)*128 + slot;
      double k[8];
#pragma unroll
      for (int u = 0; u < 8; ++u) k[u] = mkkey(cB[u], (u32)(qb + u*16), px,py,pz,ps);
#pragma unroll
      for (int u = 0; u < 8; ++u) cB[u] = pbase[(2*pair + 3)*128 + u*16 + slot];
      sort8d(k);
      low8(acc, k);
    }
    // process cA = batch 2*pair+2 ; prefetch cA <- batch 2*pair+4 (skip last)
    {
      int qb = (2*pair + 2)*128 + slot;
      double k[8];
#pragma unroll
      for (int u = 0; u < 8; ++u) k[u] = mkkey(cA[u], (u32)(qb + u*16), px,py,pz,ps);
      if (pair < 6) {
#pragma unroll
        for (int u = 0; u < 8; ++u) cA[u] = pbase[(2*pair + 4)*128 + u*16 + slot];
      }
      sort8d(k);
      low8(acc, k);
    }
  }
  {
    // final: process cB = batch 15
    int qb = 15*128 + slot;
    double k[8];
#pragma unroll
    for (int u = 0; u < 8; ++u) k[u] = mkkey(cB[u], (u32)(qb + u*16), px,py,pz,ps);
    sort8d(k);
    low8(acc, k);
  }

  // unpack into register queue (strip f64 exponent tag: bits 46-47 of the u64);
  // refill anchor = last initial entry acc[7]
  u32 OU[8], IX[8];
#pragma unroll
  for (int j = 0; j < 8; ++j) {
    u64 bb = (u64)__double_as_longlong(acc[j]);
    OU[j] = (u32)((bb & 0x0000FFFFFFFF0000ull) >> 16);
    IX[j] = (u32)(bb & 0xffffu);
  }
  u32 lou = OU[7], lix = IX[7];
  u32 cap1=0, cap2=0, cap3=0;

#pragma unroll 1
  for (int i = 0; i < 16; ++i)         // winners 0..15 -> cap1[slot==i]
    popstep(OU, IX, lou, lix, cap1, i, slot, pbase, px,py,pz,ps);
#pragma unroll 1
  for (int i = 0; i < 16; ++i)         // winners 16..31 -> cap2
    popstep(OU, IX, lou, lix, cap2, i, slot, pbase, px,py,pz,ps);
#pragma unroll 1
  for (int i = 0; i < 8; ++i)          // winners 32..39 -> cap3 (slots 0..7)
    popstep(OU, IX, lou, lix, cap3, i, slot, pbase, px,py,pz,ps);

  // ---- epilogue: geodesic sums ----
  int row = bt*P_ + prow;
  const float4* qbt = qf + (size_t)bt * P_;
  float4 qp = qf[row];

  float4 n; float d;
  n = qbt[cap1]; d = ((qp.x*n.x + qp.y*n.y) + qp.z*n.z) + qp.w*n.w;
  float g1 = 2.f * acosf(fminf(fabsf(d), 0.99999990f));
  n = qbt[cap2]; d = ((qp.x*n.x + qp.y*n.y) + qp.z*n.z) + qp.w*n.w;
  float g2 = 2.f * acosf(fminf(fabsf(d), 0.99999990f));
  n = qbt[cap3]; d = ((qp.x*n.x + qp.y*n.y) + qp.z*n.z) + qp.w*n.w;
  float g3 = (slot < 8) ? 2.f * acosf(fminf(fabsf(d), 0.99999990f)) : 0.f;

  float s40 = bfly16_sum_f32(g1 + g2 + g3);
  float s15 = bfly16_sum_f32((slot < 15) ? g1 : 0.f);
  float s5  = bfly16_sum_f32((slot < 5)  ? g1 : 0.f);

  if (slot == 0) {
    S[0*ROWS + row] = s5  / 5.f;
    S[1*ROWS + row] = s15 / 15.f;
    S[2*ROWS + row] = s40 / 40.f;
  }
}

// ---------------- Kernel E: mean over t, median, output (1 block per scale) ----
__global__ __launch_bounds__(1024) void kE_final(const float* __restrict__ S,
                                                 float* __restrict__ out) {
  int k = blockIdx.x;                  // scale index 0..2
  int tid = threadIdx.x;
  __shared__ float srt[4096];
  const float* Sk = S + (size_t)k * ROWS;
  float m[4];
#pragma unroll
  for (int u = 0; u < 4; ++u) {
    int j = tid + u*1024;              // j = b*2048 + p
    int b = j >> 11, p = j & 2047;
    float acc = 0.f;
#pragma unroll
    for (int t = 0; t < 7; ++t) acc += Sk[(b*7 + t)*2048 + p];
    m[u] = acc / 7.f;
    srt[j] = m[u];
  }
  __syncthreads();
  for (int size = 2; size <= 4096; size <<= 1) {
    for (int stride = size >> 1; stride > 0; stride >>= 1) {
      for (int c = tid; c < 2048; c += 1024) {
        int i = 2*c - (c & (stride - 1));
        int j = i + stride;
        bool up = ((i & size) == 0);
        float a = srt[i], bb = srt[j];
        if ((a > bb) == up) { srt[i] = bb; srt[j] = a; }
      }
      __syncthreads();
    }
  }
  float scale = fmaxf(srt[2047], 1e-6f);   // lower median of 4096
  bool pos = srt[4095] > 0.f;
#pragma unroll
  for (int u = 0; u < 4; ++u) {
    int j = tid + u*1024;
    int b = j >> 11, p = j & 2047;
    float r = pos ? expf(-m[u]/scale) : 1.f;
    float* ob = out + ((size_t)(b*3 + k)*8)*2048 + p;
#pragma unroll
    for (int f = 0; f < 8; ++f) ob[f*2048] = r;
  }
}

extern "C" void kernel_launch(void* const* d_in, const int* in_sizes, int n_in,
                              void* d_out, int out_size, void* d_ws, size_t ws_size,
                              hipStream_t stream) {
  (void)in_sizes; (void)n_in; (void)out_size; (void)ws_size;
  const float4* pts = (const float4*)d_in[0];
  float* ws = (float*)d_ws;
  float4* bq   = (float4*)ws;                     // B*F*P*4   = 131072 floats
  float4* qfw  = (float4*)(ws + 131072);          // B*T*P*4   = 114688 floats
  float*  S    = ws + 131072 + 114688;            // 3*ROWS    =  86016 floats
  float4* pts2 = (float4*)(ws + 131072 + 114688 + 86016);  // B*F*P*4 = 131072 floats
  float*  out = (float*)d_out;

  hipLaunchKernelGGL(kA_bearing, dim3(B_*F_), dim3(256), 0, stream, pts, bq, pts2);
  hipLaunchKernelGGL(kB_qfwd,    dim3(ROWS/256), dim3(256), 0, stream, bq, qfw);
  hipLaunchKernelGGL(kC_select,  dim3(ROWS/16), dim3(256), 0, stream, pts2, qfw, S);
  hipLaunchKernelGGL(kE_final,   dim3(3), dim3(1024), 0, stream, S, out);
}